// Round 2
// baseline (459.353 us; speedup 1.0000x reference)
//
#include <hip/hip_runtime.h>
#include <stdint.h>

// Problem dims
#define BB   512
#define NNN  64
#define HHH  256
#define BN_  32768   // B*N
#define H2_  512
#define H3_  768

typedef unsigned short u16;
typedef unsigned int   u32;
typedef __attribute__((ext_vector_type(8)))  short bf16x8;   // 8 bf16 in 4 VGPRs
typedef __attribute__((ext_vector_type(4)))  float f32x4;
typedef __attribute__((ext_vector_type(16))) float f32x16;

__device__ __forceinline__ u16 f2bf(float f) {
  union { float f; u32 u; } x; x.f = f;
  return (u16)((x.u + 0x7fffu + ((x.u >> 16) & 1u)) >> 16);  // RNE
}
__device__ __forceinline__ float bf2f(u16 v) {
  union { u32 u; float f; } x; x.u = ((u32)v) << 16; return x.f;
}
__device__ __forceinline__ void async16(const void* g, void* l) {
  __builtin_amdgcn_global_load_lds(
      (const __attribute__((address_space(1))) u32*)(uintptr_t)g,
      (__attribute__((address_space(3))) u32*)(uintptr_t)l, 16, 0, 0);
}
__device__ __forceinline__ float sigmoidf_(float x) { return 1.0f / (1.0f + __expf(-x)); }
__device__ __forceinline__ float tanhf_(float x)    { return 2.0f / (1.0f + __expf(-2.0f * x)) - 1.0f; }

// ---------------------------------------------------------------- K0: f32 weights -> bf16 wcat
// wcat layout (elems): [W_in 65536 | W_out 65536 | w_ih 393216 | w_hh 196608]
__global__ __launch_bounds__(256) void k_convert(const float* __restrict__ W_in,
                                                 const float* __restrict__ W_out,
                                                 const float* __restrict__ w_ih,
                                                 const float* __restrict__ w_hh,
                                                 u16* __restrict__ wcat) {
  int i = blockIdx.x * 256 + threadIdx.x;
  const float* src; int off;
  if (i < 65536)       { src = W_in;  off = i; }
  else if (i < 131072) { src = W_out; off = i - 65536; }
  else if (i < 524288) { src = w_ih;  off = i - 131072; }
  else                 { src = w_hh;  off = i - 524288; }
  wcat[i] = f2bf(src[off]);
}

// ---------------------------------------------------------------- K1: gather + L2 norm
__global__ __launch_bounds__(256) void k_gather_norm(const int* __restrict__ idx,
                                                     const float* __restrict__ emb,
                                                     u16* __restrict__ h) {
  int row  = blockIdx.x * 4 + (threadIdx.x >> 6);
  int lane = threadIdx.x & 63;
  int e = idx[row];
  float4 v = *(const float4*)(emb + (size_t)e * HHH + lane * 4);
  float s = v.x * v.x + v.y * v.y + v.z * v.z + v.w * v.w;
  for (int off = 32; off; off >>= 1) s += __shfl_xor(s, off, 64);
  float sc = 1.0f / (sqrtf(s) + 1e-12f);
  ushort4 o;
  o.x = f2bf(v.x * sc); o.y = f2bf(v.y * sc); o.z = f2bf(v.z * sc); o.w = f2bf(v.w * sc);
  *(ushort4*)(h + (size_t)row * HHH + lane * 4) = o;
}

// ---------------------------------------------------------------- K2: HioT = wcat @ h^T (+bias)
// A-op = h node rows (M), B-op = wcat channel rows (N) -> C[node][ch]; epilogue transposes
// through LDS so HBM stores are 16B/lane coalesced. HioT[b][c][node64].
__global__ __launch_bounds__(256) void k_hio(const u16* __restrict__ h,
                                             const u16* __restrict__ wcat,
                                             const float* __restrict__ b_in,
                                             const float* __restrict__ b_out,
                                             u16* __restrict__ HioT) {
  __shared__ __align__(16) char smem[34816];         // phase1: Ws 16K | Hs 16K ; phase2: Tt [128][136] u16
  u16* Ws = (u16*)smem;
  u16* Hs = Ws + 8192;
  u16* Tt = (u16*)smem;
  int c0 = blockIdx.y * 128;
  int n0 = blockIdx.x * 128;
  int t = threadIdx.x, w = t >> 6, lane = t & 63;
  int wm = w >> 1, wn = w & 1;    // wm: node half, wn: channel half
  int rsub = lane >> 3, kofs = ((lane & 7) ^ rsub) << 3;
  const u16* wbase = wcat + (size_t)c0 * 256;
  f32x4 acc[4][4];   // [node-tile][ch-tile]
  for (int a = 0; a < 4; ++a) for (int b = 0; b < 4; ++b) acc[a][b] = (f32x4)0.0f;

  for (int kt = 0; kt < 4; ++kt) {
    int k0 = kt * 64;
    for (int i = 0; i < 4; ++i) {
      int r = 32 * w + 8 * i;
      async16(wbase + (size_t)(r + rsub) * 256 + k0 + kofs, &Ws[r * 64]);
      async16(h + (size_t)(n0 + r + rsub) * 256 + k0 + kofs, &Hs[r * 64]);
    }
    __syncthreads();
    for (int ks = 0; ks < 2; ++ks) {
      int c = ks * 4 + (lane >> 4);
      bf16x8 af[4], bf[4];
      for (int mt = 0; mt < 4; ++mt) {
        int r = 64 * wm + 16 * mt + (lane & 15);
        af[mt] = *(const bf16x8*)(Hs + r * 64 + ((c ^ (r & 7)) << 3));
      }
      for (int nt = 0; nt < 4; ++nt) {
        int r = 64 * wn + 16 * nt + (lane & 15);
        bf[nt] = *(const bf16x8*)(Ws + r * 64 + ((c ^ (r & 7)) << 3));
      }
      for (int mt = 0; mt < 4; ++mt)
        for (int nt = 0; nt < 4; ++nt)
          acc[mt][nt] = __builtin_amdgcn_mfma_f32_16x16x32_bf16(af[mt], bf[nt], acc[mt][nt], 0, 0, 0);
    }
    __syncthreads();
  }
  // epilogue: bias + pack 4 consecutive nodes per b64 into Tt[ch][node(pad 136)]
  for (int nt = 0; nt < 4; ++nt) {
    int chl = 64 * wn + 16 * nt + (lane & 15);
    int cg = c0 + chl;
    float bv = (cg < 256) ? b_in[cg] : b_out[cg - 256];
    for (int mt = 0; mt < 4; ++mt) {
      int nb = 64 * wm + 16 * mt + (lane >> 4) * 4;
      u32 lo = (u32)f2bf(acc[mt][nt][0] + bv) | ((u32)f2bf(acc[mt][nt][1] + bv) << 16);
      u32 hi = (u32)f2bf(acc[mt][nt][2] + bv) | ((u32)f2bf(acc[mt][nt][3] + bv) << 16);
      *(uint2*)(Tt + chl * 136 + nb) = make_uint2(lo, hi);
    }
  }
  __syncthreads();
  // coalesced store: 8 iters, 16B per thread
  for (int it = 0; it < 8; ++it) {
    int id = it * 256 + t;                 // [128 ch][2 nblk][8 chunk]
    int ch = id >> 4, nb = (id >> 3) & 1, c8 = id & 7;
    uint4 v = *(const uint4*)(Tt + ch * 136 + nb * 64 + c8 * 8);
    *(uint4*)(HioT + (size_t)((n0 >> 6) + nb) * 32768 + (size_t)(c0 + ch) * 64 + c8 * 8) = v;
  }
}

// ---------------------------------------------------------------- K3: per-batch adjacency matmul
// A-op = HioT channel rows (M), B-op = A node rows (N) -> C[ch][node]; reg-quads pack 4
// consecutive ch -> LDS transpose -> coalesced 16B stores of inp[node][ch].
__global__ __launch_bounds__(256) void k_amul(const float* __restrict__ Ag,
                                              const u16* __restrict__ HioT,
                                              const float* __restrict__ b_iah,
                                              const float* __restrict__ b_oah,
                                              u16* __restrict__ inp) {
  __shared__ __align__(16) u16 As[64 * 136];   // A[b]: 64 x 128 bf16, pad->136
  __shared__ __align__(16) u16 Hs[256 * 64];   // phase: HioT half (swz) ; then Tt2 [64 node][256 ch] xor16B
  int b = blockIdx.x;
  int t = threadIdx.x, w = t >> 6, lane = t & 63;
  int rsub = lane >> 3, kofs = ((lane & 7) ^ rsub) << 3;
  {
    int r = t >> 2, q = t & 3;
    const float4* src = (const float4*)(Ag + (size_t)b * 8192 + r * 128 + q * 32);
    u16* dst = As + r * 136 + q * 32;
    for (int j = 0; j < 8; ++j) {
      float4 v = src[j];
      ushort4 o;
      o.x = f2bf(v.x); o.y = f2bf(v.y); o.z = f2bf(v.z); o.w = f2bf(v.w);
      *(ushort4*)(dst + j * 4) = o;
    }
  }
  for (int co = 0; co < 2; ++co) {
    __syncthreads();
    for (int i = 0; i < 2; ++i) {
      int rb = 64 * w + 32 * i;
      for (int s = 0; s < 4; ++s)
        async16(HioT + (size_t)b * 32768 + (size_t)(co * 256 + rb + 8 * s + rsub) * 64 + kofs,
                &Hs[(rb + 8 * s) * 64]);
    }
    __syncthreads();
    f32x4 acc[4][4];   // [ch-tile][node-tile]
    for (int a = 0; a < 4; ++a) for (int c = 0; c < 4; ++c) acc[a][c] = (f32x4)0.0f;
    for (int ks = 0; ks < 2; ++ks) {
      int c = ks * 4 + (lane >> 4);            // node-chunk
      int kk = co * 64 + ks * 32 + (lane >> 4) * 8;
      bf16x8 af[4], bf[4];
      for (int mt = 0; mt < 4; ++mt) {
        int r = 64 * w + 16 * mt + (lane & 15);   // ch row (within 256-half)
        af[mt] = *(const bf16x8*)(Hs + r * 64 + ((c ^ (r & 7)) << 3));
      }
      for (int nt = 0; nt < 4; ++nt) {
        int n = 16 * nt + (lane & 15);
        bf[nt] = *(const bf16x8*)(As + n * 136 + kk);
      }
      for (int mt = 0; mt < 4; ++mt)
        for (int nt = 0; nt < 4; ++nt)
          acc[mt][nt] = __builtin_amdgcn_mfma_f32_16x16x32_bf16(af[mt], bf[nt], acc[mt][nt], 0, 0, 0);
    }
    __syncthreads();   // done reading Hs; reuse as Tt2
    const float* bias = (co == 0) ? b_iah : b_oah;
    u16* Tt2 = Hs;     // [64 node][256 ch], 16B-chunk xor swizzle by (node&7)
    for (int mt = 0; mt < 4; ++mt) {
      int chb = 64 * w + 16 * mt + (lane >> 4) * 4;
      float b0 = bias[chb], b1 = bias[chb + 1], b2 = bias[chb + 2], b3 = bias[chb + 3];
      for (int nt = 0; nt < 4; ++nt) {
        int node = 16 * nt + (lane & 15);
        u32 lo = (u32)f2bf(acc[mt][nt][0] + b0) | ((u32)f2bf(acc[mt][nt][1] + b1) << 16);
        u32 hi = (u32)f2bf(acc[mt][nt][2] + b2) | ((u32)f2bf(acc[mt][nt][3] + b3) << 16);
        int byte = node * 512 + (((chb >> 3) ^ (node & 7)) << 4) + (chb & 7) * 2;
        *(uint2*)((char*)Tt2 + byte) = make_uint2(lo, hi);
      }
    }
    __syncthreads();
    for (int it = 0; it < 8; ++it) {
      int id = it * 256 + t;                 // [64 node][32 chunk16B]
      int node = id >> 5, c = id & 31;
      uint4 v = *(const uint4*)((char*)Tt2 + node * 512 + ((c ^ (node & 7)) << 4));
      *(uint4*)(inp + ((size_t)b * 64 + node) * 512 + co * 256 + c * 8) = v;
    }
  }
}

// ---------------------------------------------------------------- K4: fused gate GEMM + GRU (32x32x16)
// v3: weights back in LDS (no long-lived load regs -> no spill), BK=32, LDS double-buffered
// (2 x (4KB X + 24KB W) = 56KB). T3 minimal 2-phase pipeline: stage(kt+1) issued BEFORE
// compute(kt), single __syncthreads per kt -> global latency hides under compute instead of
// round-0's per-kt full-drain stall. LDS lines = 128B holding 2 rows x 32 elems; 16B slot
// swizzle slot = ((r&1)*4 + c) ^ ((r>>1)&7): ds_read_b128 fragments land 2 lanes/bank (free).
// Staging is global_load_lds with inverse-swizzled per-lane SOURCE (linear LDS dest).
// acc: a0=i_r+h_r, a1=i_i+h_i, a2=i_n (kt 0..15), a3=h_n (kt 16..23).
__global__ __launch_bounds__(256, 2) void k_gates(const u16* __restrict__ inp,
                                                  const u16* __restrict__ h,
                                                  const u16* __restrict__ wcat,
                                                  const float* __restrict__ b_ih,
                                                  const float* __restrict__ b_hh,
                                                  float* __restrict__ out) {
  __shared__ __align__(16) u16 Xs[2][2048];    // 8 KB  : X tile 64 rows x 32 K
  __shared__ __align__(16) u16 Ws[2][12288];   // 48 KB : 3 slabs x 128 rows x 32 K
  const u16* wih_b = wcat + 131072;   // [768,512]
  const u16* whh_b = wcat + 524288;   // [768,256]
  int m0 = blockIdx.x * 64;
  int j0 = blockIdx.y * 128;
  int t = threadIdx.x, w = t >> 6, lane = t & 63;
  int l3 = lane >> 3, q = lane & 7;
  int cpar = lane >> 5;

  // ---- staging source bases: fixed per-thread (r,c); only k-offset varies with kt ----
  // X: one call/thread, lines w*8..w*8+7. lane -> line L, slot q; logical p=q^(L&7),
  // r=2L+(p>>2), c=p&3.
  const u16 *bx_i, *bx_h;
  {
    int L = w * 8 + l3;
    int p = q ^ (L & 7);
    int r = 2 * L + (p >> 2), c = p & 3;
    bx_i = inp + (size_t)(m0 + r) * 512 + c * 8;
    bx_h = h   + (size_t)(m0 + r) * 256 + c * 8;
  }
  // W: 6 calls/thread covering 192 lines (3 slabs x 64 lines).
  const u16 *bw_i[6], *bw_h[6];
#pragma unroll
  for (int i = 0; i < 6; ++i) {
    int gL = i * 32 + w * 8 + l3;
    int s = gL >> 6, L = gL & 63;
    int p = q ^ (L & 7);
    int r = 2 * L + (p >> 2), c = p & 3;
    int grow = s * 256 + j0 + r;
    bw_i[i] = wih_b + (size_t)grow * 512 + c * 8;
    bw_h[i] = whh_b + (size_t)grow * 256 + c * 8;
  }
  // ---- compute-phase lane constants ----
  int rA = lane & 31;
  int LA = rA >> 1;                    // mt=1 adds 16 lines; (LA+16)&7 == LA&7
  int pA = (rA & 1) * 4, sA = LA & 7;
  int eA0 = LA * 64, eA1 = (LA + 16) * 64;
  int rW = 32 * w + rA;
  int LW = rW >> 1, pW = (rW & 1) * 4, sW = LW & 7;
  int eW = LW * 64;

  f32x16 acc[4][2];
#pragma unroll
  for (int g = 0; g < 4; ++g)
#pragma unroll
    for (int mt = 0; mt < 2; ++mt) acc[g][mt] = (f32x16)0.0f;

  // prologue: stage kt=0 into buf0
  {
    async16(bx_i, &Xs[0][w * 8 * 64]);
#pragma unroll
    for (int i = 0; i < 6; ++i)
      async16(bw_i[i], &Ws[0][(i * 32 + w * 8) * 64]);
  }

#pragma unroll 1
  for (int kt = 0; kt < 24; ++kt) {
    // 1) stage kt+1 into the other buffer (issued BEFORE compute -> latency hides)
    int kn = kt + 1;
    if (kn < 24) {
      int buf = kn & 1;
      u16* Xd = &Xs[buf][w * 8 * 64];
      u16* Wd = &Ws[buf][0];
      if (kn < 16) {
        int koff = kn * 32;
        async16(bx_i + koff, Xd);
#pragma unroll
        for (int i = 0; i < 6; ++i)
          async16(bw_i[i] + koff, Wd + (i * 32 + w * 8) * 64);
      } else {
        int koff = (kn - 16) * 32;
        async16(bx_h + koff, Xd);
#pragma unroll
        for (int i = 0; i < 6; ++i)
          async16(bw_h[i] + koff, Wd + (i * 32 + w * 8) * 64);
      }
    }
    __builtin_amdgcn_sched_barrier(0);  // pin: stage issues stay above the ds_reads
    // 2) compute kt from buf kt&1
    const u16* Xb = &Xs[kt & 1][0];
    const u16* Wb = &Ws[kt & 1][0];
    if (kt < 16) {                      // gi phase: slab2 -> a2 (i_n)
#pragma unroll
      for (int ks = 0; ks < 2; ++ks) {
        int c = ks * 2 + cpar;
        int slA = ((pA + c) ^ sA) << 3;
        int slW = ((pW + c) ^ sW) << 3;
        bf16x8 af0 = *(const bf16x8*)(Xb + eA0 + slA);
        bf16x8 af1 = *(const bf16x8*)(Xb + eA1 + slA);
        bf16x8 b0 = *(const bf16x8*)(Wb + eW + slW);
        bf16x8 b1 = *(const bf16x8*)(Wb + 4096 + eW + slW);
        bf16x8 b2 = *(const bf16x8*)(Wb + 8192 + eW + slW);
        acc[0][0] = __builtin_amdgcn_mfma_f32_32x32x16_bf16(af0, b0, acc[0][0], 0, 0, 0);
        acc[0][1] = __builtin_amdgcn_mfma_f32_32x32x16_bf16(af1, b0, acc[0][1], 0, 0, 0);
        acc[1][0] = __builtin_amdgcn_mfma_f32_32x32x16_bf16(af0, b1, acc[1][0], 0, 0, 0);
        acc[1][1] = __builtin_amdgcn_mfma_f32_32x32x16_bf16(af1, b1, acc[1][1], 0, 0, 0);
        acc[2][0] = __builtin_amdgcn_mfma_f32_32x32x16_bf16(af0, b2, acc[2][0], 0, 0, 0);
        acc[2][1] = __builtin_amdgcn_mfma_f32_32x32x16_bf16(af1, b2, acc[2][1], 0, 0, 0);
      }
    } else {                            // gh phase: slab2 -> a3 (h_n)
#pragma unroll
      for (int ks = 0; ks < 2; ++ks) {
        int c = ks * 2 + cpar;
        int slA = ((pA + c) ^ sA) << 3;
        int slW = ((pW + c) ^ sW) << 3;
        bf16x8 af0 = *(const bf16x8*)(Xb + eA0 + slA);
        bf16x8 af1 = *(const bf16x8*)(Xb + eA1 + slA);
        bf16x8 b0 = *(const bf16x8*)(Wb + eW + slW);
        bf16x8 b1 = *(const bf16x8*)(Wb + 4096 + eW + slW);
        bf16x8 b2 = *(const bf16x8*)(Wb + 8192 + eW + slW);
        acc[0][0] = __builtin_amdgcn_mfma_f32_32x32x16_bf16(af0, b0, acc[0][0], 0, 0, 0);
        acc[0][1] = __builtin_amdgcn_mfma_f32_32x32x16_bf16(af1, b0, acc[0][1], 0, 0, 0);
        acc[1][0] = __builtin_amdgcn_mfma_f32_32x32x16_bf16(af0, b1, acc[1][0], 0, 0, 0);
        acc[1][1] = __builtin_amdgcn_mfma_f32_32x32x16_bf16(af1, b1, acc[1][1], 0, 0, 0);
        acc[3][0] = __builtin_amdgcn_mfma_f32_32x32x16_bf16(af0, b2, acc[3][0], 0, 0, 0);
        acc[3][1] = __builtin_amdgcn_mfma_f32_32x32x16_bf16(af1, b2, acc[3][1], 0, 0, 0);
      }
    }
    // 3) drain stage(kt+1) + barrier (loads had the whole compute phase to land)
    __syncthreads();
  }
  // epilogue: stage h tile [64][128] into Hh (aliases Ws), 16B-chunk xor swizzle by row
  u16* Hh = (u16*)&Ws[0][0];
  {
    int rsub4 = lane >> 4, cch = lane & 15;
#pragma unroll
    for (int i = 0; i < 4; ++i) {
      int og = i * 4 + w, r0e = og * 4;
      int kofsH = ((cch ^ ((r0e & 4) | rsub4)) << 3);
      async16(h + (size_t)(m0 + r0e + rsub4) * 256 + j0 + kofsH, &Hh[r0e * 128]);
    }
  }
  __syncthreads();
  // gates in-register; hv from Hh; hy -> F f32[64][128] (aliases Ws + 16KB)
  float* F = (float*)((char*)&Ws[0][0] + 16384);
  int jl = 32 * w + (lane & 31);
  int j = j0 + jl;
  float brs = b_ih[j] + b_hh[j];
  float bis = b_ih[256 + j] + b_hh[256 + j];
  float bin = b_ih[512 + j];
  float bhn = b_hh[512 + j];
  int jc = jl >> 3, je = (jl & 7) * 2;
#pragma unroll
  for (int mt = 0; mt < 2; ++mt) {
#pragma unroll
    for (int e = 0; e < 16; ++e) {
      int row = (e & 3) + 8 * (e >> 2) + 4 * (lane >> 5);
      int mloc = 32 * mt + row;
      float r  = sigmoidf_(acc[0][mt][e] + brs);
      float ig = sigmoidf_(acc[1][mt][e] + bis);
      float hn = acc[3][mt][e] + bhn;
      float ng = tanhf_(acc[2][mt][e] + bin + r * hn);
      float hv = bf2f(*(const u16*)((char*)Hh + mloc * 256 + ((jc ^ (mloc & 7)) << 4) + je));
      F[mloc * 128 + jl] = ng + ig * (hv - ng);
    }
  }
  __syncthreads();
  for (int it = 0; it < 16; ++it) {
    int id = it * 256 + t;            // [64 m][64 j-pairs]
    int mloc = id >> 6, jp = (id & 63) * 2;
    float2 v = *(const float2*)(F + mloc * 128 + jp);
    *(float2*)(out + (size_t)(m0 + mloc) * 256 + j0 + jp) = v;
  }
}

extern "C" void kernel_launch(void* const* d_in, const int* in_sizes, int n_in,
                              void* d_out, int out_size, void* d_ws, size_t ws_size,
                              hipStream_t stream) {
  (void)in_sizes; (void)n_in; (void)out_size; (void)ws_size;
  const int*   inputs = (const int*)d_in[0];
  const float* A      = (const float*)d_in[1];
  const float* emb    = (const float*)d_in[2];
  const float* W_in   = (const float*)d_in[3];
  const float* b_in   = (const float*)d_in[4];
  const float* W_out  = (const float*)d_in[5];
  const float* b_out  = (const float*)d_in[6];
  const float* w_ih   = (const float*)d_in[7];
  const float* b_ih   = (const float*)d_in[8];
  const float* w_hh   = (const float*)d_in[9];
  const float* b_hh   = (const float*)d_in[10];
  const float* b_iah  = (const float*)d_in[11];
  const float* b_oah  = (const float*)d_in[12];
  float* out = (float*)d_out;

  u16* h    = (u16*)d_ws;                 // BN*256 bf16 = 16.8 MB
  u16* HioT = h + (size_t)BN_ * HHH;      // 33.6 MB
  u16* inp  = HioT + (size_t)BN_ * H2_;   // 33.6 MB
  u16* wcat = inp + (size_t)BN_ * H2_;    // 1.44 MB

  k_convert<<<2816, 256, 0, stream>>>(W_in, W_out, w_ih, w_hh, wcat);
  k_gather_norm<<<BN_ / 4, 256, 0, stream>>>(inputs, emb, h);
  k_hio<<<dim3(BN_ / 128, 4), 256, 0, stream>>>(h, wcat, b_in, b_out, HioT);
  k_amul<<<BB, 256, 0, stream>>>(A, HioT, b_iah, b_oah, inp);
  k_gates<<<dim3(BN_ / 64, 2), 256, 0, stream>>>(inp, h, wcat, b_ih, b_hh, out);
}

// Round 3
// 435.760 us; speedup vs baseline: 1.0541x; 1.0541x over previous
//
#include <hip/hip_runtime.h>
#include <stdint.h>

// Problem dims
#define BB   512
#define NNN  64
#define HHH  256
#define BN_  32768   // B*N
#define H2_  512
#define H3_  768

typedef unsigned short u16;
typedef unsigned int   u32;
typedef __attribute__((ext_vector_type(8)))  short bf16x8;   // 8 bf16 in 4 VGPRs
typedef __attribute__((ext_vector_type(4)))  float f32x4;
typedef __attribute__((ext_vector_type(16))) float f32x16;

__device__ __forceinline__ u16 f2bf(float f) {
  union { float f; u32 u; } x; x.f = f;
  return (u16)((x.u + 0x7fffu + ((x.u >> 16) & 1u)) >> 16);  // RNE
}
__device__ __forceinline__ float bf2f(u16 v) {
  union { u32 u; float f; } x; x.u = ((u32)v) << 16; return x.f;
}
__device__ __forceinline__ void async16(const void* g, void* l) {
  __builtin_amdgcn_global_load_lds(
      (const __attribute__((address_space(1))) u32*)(uintptr_t)g,
      (__attribute__((address_space(3))) u32*)(uintptr_t)l, 16, 0, 0);
}
__device__ __forceinline__ float sigmoidf_(float x) { return 1.0f / (1.0f + __expf(-x)); }
__device__ __forceinline__ float tanhf_(float x)    { return 2.0f / (1.0f + __expf(-2.0f * x)) - 1.0f; }

// ---------------------------------------------------------------- K0: f32 weights -> bf16 wcat
// wcat layout (elems): [W_in 65536 | W_out 65536 | w_ih 393216 | w_hh 196608]
__global__ __launch_bounds__(256) void k_convert(const float* __restrict__ W_in,
                                                 const float* __restrict__ W_out,
                                                 const float* __restrict__ w_ih,
                                                 const float* __restrict__ w_hh,
                                                 u16* __restrict__ wcat) {
  int i = blockIdx.x * 256 + threadIdx.x;
  const float* src; int off;
  if (i < 65536)       { src = W_in;  off = i; }
  else if (i < 131072) { src = W_out; off = i - 65536; }
  else if (i < 524288) { src = w_ih;  off = i - 131072; }
  else                 { src = w_hh;  off = i - 524288; }
  wcat[i] = f2bf(src[off]);
}

// ---------------------------------------------------------------- K1: gather + L2 norm
__global__ __launch_bounds__(256) void k_gather_norm(const int* __restrict__ idx,
                                                     const float* __restrict__ emb,
                                                     u16* __restrict__ h) {
  int row  = blockIdx.x * 4 + (threadIdx.x >> 6);
  int lane = threadIdx.x & 63;
  int e = idx[row];
  float4 v = *(const float4*)(emb + (size_t)e * HHH + lane * 4);
  float s = v.x * v.x + v.y * v.y + v.z * v.z + v.w * v.w;
  for (int off = 32; off; off >>= 1) s += __shfl_xor(s, off, 64);
  float sc = 1.0f / (sqrtf(s) + 1e-12f);
  ushort4 o;
  o.x = f2bf(v.x * sc); o.y = f2bf(v.y * sc); o.z = f2bf(v.z * sc); o.w = f2bf(v.w * sc);
  *(ushort4*)(h + (size_t)row * HHH + lane * 4) = o;
}

// ---------------------------------------------------------------- K2: HioT = wcat @ h^T (+bias)
// A-op = h node rows (M), B-op = wcat channel rows (N) -> C[node][ch]; epilogue transposes
// through LDS so HBM stores are 16B/lane coalesced. HioT[b][c][node64].
__global__ __launch_bounds__(256) void k_hio(const u16* __restrict__ h,
                                             const u16* __restrict__ wcat,
                                             const float* __restrict__ b_in,
                                             const float* __restrict__ b_out,
                                             u16* __restrict__ HioT) {
  __shared__ __align__(16) char smem[34816];         // phase1: Ws 16K | Hs 16K ; phase2: Tt [128][136] u16
  u16* Ws = (u16*)smem;
  u16* Hs = Ws + 8192;
  u16* Tt = (u16*)smem;
  int c0 = blockIdx.y * 128;
  int n0 = blockIdx.x * 128;
  int t = threadIdx.x, w = t >> 6, lane = t & 63;
  int wm = w >> 1, wn = w & 1;    // wm: node half, wn: channel half
  int rsub = lane >> 3, kofs = ((lane & 7) ^ rsub) << 3;
  const u16* wbase = wcat + (size_t)c0 * 256;
  f32x4 acc[4][4];   // [node-tile][ch-tile]
  for (int a = 0; a < 4; ++a) for (int b = 0; b < 4; ++b) acc[a][b] = (f32x4)0.0f;

  for (int kt = 0; kt < 4; ++kt) {
    int k0 = kt * 64;
    for (int i = 0; i < 4; ++i) {
      int r = 32 * w + 8 * i;
      async16(wbase + (size_t)(r + rsub) * 256 + k0 + kofs, &Ws[r * 64]);
      async16(h + (size_t)(n0 + r + rsub) * 256 + k0 + kofs, &Hs[r * 64]);
    }
    __syncthreads();
    for (int ks = 0; ks < 2; ++ks) {
      int c = ks * 4 + (lane >> 4);
      bf16x8 af[4], bf[4];
      for (int mt = 0; mt < 4; ++mt) {
        int r = 64 * wm + 16 * mt + (lane & 15);
        af[mt] = *(const bf16x8*)(Hs + r * 64 + ((c ^ (r & 7)) << 3));
      }
      for (int nt = 0; nt < 4; ++nt) {
        int r = 64 * wn + 16 * nt + (lane & 15);
        bf[nt] = *(const bf16x8*)(Ws + r * 64 + ((c ^ (r & 7)) << 3));
      }
      for (int mt = 0; mt < 4; ++mt)
        for (int nt = 0; nt < 4; ++nt)
          acc[mt][nt] = __builtin_amdgcn_mfma_f32_16x16x32_bf16(af[mt], bf[nt], acc[mt][nt], 0, 0, 0);
    }
    __syncthreads();
  }
  // epilogue: bias + pack 4 consecutive nodes per b64 into Tt[ch][node(pad 136)]
  for (int nt = 0; nt < 4; ++nt) {
    int chl = 64 * wn + 16 * nt + (lane & 15);
    int cg = c0 + chl;
    float bv = (cg < 256) ? b_in[cg] : b_out[cg - 256];
    for (int mt = 0; mt < 4; ++mt) {
      int nb = 64 * wm + 16 * mt + (lane >> 4) * 4;
      u32 lo = (u32)f2bf(acc[mt][nt][0] + bv) | ((u32)f2bf(acc[mt][nt][1] + bv) << 16);
      u32 hi = (u32)f2bf(acc[mt][nt][2] + bv) | ((u32)f2bf(acc[mt][nt][3] + bv) << 16);
      *(uint2*)(Tt + chl * 136 + nb) = make_uint2(lo, hi);
    }
  }
  __syncthreads();
  // coalesced store: 8 iters, 16B per thread
  for (int it = 0; it < 8; ++it) {
    int id = it * 256 + t;                 // [128 ch][2 nblk][8 chunk]
    int ch = id >> 4, nb = (id >> 3) & 1, c8 = id & 7;
    uint4 v = *(const uint4*)(Tt + ch * 136 + nb * 64 + c8 * 8);
    *(uint4*)(HioT + (size_t)((n0 >> 6) + nb) * 32768 + (size_t)(c0 + ch) * 64 + c8 * 8) = v;
  }
}

// ---------------------------------------------------------------- K3: per-batch adjacency matmul
// A-op = HioT channel rows (M), B-op = A node rows (N) -> C[ch][node]; reg-quads pack 4
// consecutive ch -> LDS transpose -> coalesced 16B stores of inp[node][ch].
__global__ __launch_bounds__(256) void k_amul(const float* __restrict__ Ag,
                                              const u16* __restrict__ HioT,
                                              const float* __restrict__ b_iah,
                                              const float* __restrict__ b_oah,
                                              u16* __restrict__ inp) {
  __shared__ __align__(16) u16 As[64 * 136];   // A[b]: 64 x 128 bf16, pad->136
  __shared__ __align__(16) u16 Hs[256 * 64];   // phase: HioT half (swz) ; then Tt2 [64 node][256 ch] xor16B
  int b = blockIdx.x;
  int t = threadIdx.x, w = t >> 6, lane = t & 63;
  int rsub = lane >> 3, kofs = ((lane & 7) ^ rsub) << 3;
  {
    int r = t >> 2, q = t & 3;
    const float4* src = (const float4*)(Ag + (size_t)b * 8192 + r * 128 + q * 32);
    u16* dst = As + r * 136 + q * 32;
    for (int j = 0; j < 8; ++j) {
      float4 v = src[j];
      ushort4 o;
      o.x = f2bf(v.x); o.y = f2bf(v.y); o.z = f2bf(v.z); o.w = f2bf(v.w);
      *(ushort4*)(dst + j * 4) = o;
    }
  }
  for (int co = 0; co < 2; ++co) {
    __syncthreads();
    for (int i = 0; i < 2; ++i) {
      int rb = 64 * w + 32 * i;
      for (int s = 0; s < 4; ++s)
        async16(HioT + (size_t)b * 32768 + (size_t)(co * 256 + rb + 8 * s + rsub) * 64 + kofs,
                &Hs[(rb + 8 * s) * 64]);
    }
    __syncthreads();
    f32x4 acc[4][4];   // [ch-tile][node-tile]
    for (int a = 0; a < 4; ++a) for (int c = 0; c < 4; ++c) acc[a][c] = (f32x4)0.0f;
    for (int ks = 0; ks < 2; ++ks) {
      int c = ks * 4 + (lane >> 4);            // node-chunk
      int kk = co * 64 + ks * 32 + (lane >> 4) * 8;
      bf16x8 af[4], bf[4];
      for (int mt = 0; mt < 4; ++mt) {
        int r = 64 * w + 16 * mt + (lane & 15);   // ch row (within 256-half)
        af[mt] = *(const bf16x8*)(Hs + r * 64 + ((c ^ (r & 7)) << 3));
      }
      for (int nt = 0; nt < 4; ++nt) {
        int n = 16 * nt + (lane & 15);
        bf[nt] = *(const bf16x8*)(As + n * 136 + kk);
      }
      for (int mt = 0; mt < 4; ++mt)
        for (int nt = 0; nt < 4; ++nt)
          acc[mt][nt] = __builtin_amdgcn_mfma_f32_16x16x32_bf16(af[mt], bf[nt], acc[mt][nt], 0, 0, 0);
    }
    __syncthreads();   // done reading Hs; reuse as Tt2
    const float* bias = (co == 0) ? b_iah : b_oah;
    u16* Tt2 = Hs;     // [64 node][256 ch], 16B-chunk xor swizzle by (node&7)
    for (int mt = 0; mt < 4; ++mt) {
      int chb = 64 * w + 16 * mt + (lane >> 4) * 4;
      float b0 = bias[chb], b1 = bias[chb + 1], b2 = bias[chb + 2], b3 = bias[chb + 3];
      for (int nt = 0; nt < 4; ++nt) {
        int node = 16 * nt + (lane & 15);
        u32 lo = (u32)f2bf(acc[mt][nt][0] + b0) | ((u32)f2bf(acc[mt][nt][1] + b1) << 16);
        u32 hi = (u32)f2bf(acc[mt][nt][2] + b2) | ((u32)f2bf(acc[mt][nt][3] + b3) << 16);
        int byte = node * 512 + (((chb >> 3) ^ (node & 7)) << 4) + (chb & 7) * 2;
        *(uint2*)((char*)Tt2 + byte) = make_uint2(lo, hi);
      }
    }
    __syncthreads();
    for (int it = 0; it < 8; ++it) {
      int id = it * 256 + t;                 // [64 node][32 chunk16B]
      int node = id >> 5, c = id & 31;
      uint4 v = *(const uint4*)((char*)Tt2 + node * 512 + ((c ^ (node & 7)) << 4));
      *(uint4*)(inp + ((size_t)b * 64 + node) * 512 + co * 256 + c * 8) = v;
    }
  }
}

// ---------------------------------------------------------------- K4: fused gate GEMM + GRU (32x32x16)
// v4 = round-0 structure (single-buffered, stage->sync->compute->sync; known spill-free at
// 120 arch VGPR + 128 acc) with the LDS layout changed to K-MAJOR LINEAR 16B granules:
//   Xs granule(kc,row)      = kc*64  + row   (kc 0..7, row 0..63)
//   Ws granule(s,kc,row)    = (s*8+kc)*128 + row   (s 0..2 gate slab, row 0..127 j-col)
// Effects: (1) every ds_read_b128 is contiguous 512B per half-wave -> zero bank conflicts
// (was 3.93M: row-major line stride 128B == bank period -> 4-way); (2) fragment addresses
// are per-lane base + compile-time immediate (s*16384 + ks*4096 / ks*2048) -> inner-loop
// address VALU ~0 (VALUBusy was 39%); (3) staging sources are per-lane row pointers with
// small per-call adds; LDS dest stays wave-uniform + lane*16 (global_load_lds contract).
// Fragment lane->(row,k) mappings are UNCHANGED vs round-0, so epilogue math is identical.
__global__ __launch_bounds__(256, 2) void k_gates(const u16* __restrict__ inp,
                                                  const u16* __restrict__ h,
                                                  const u16* __restrict__ wcat,
                                                  const float* __restrict__ b_ih,
                                                  const float* __restrict__ b_hh,
                                                  float* __restrict__ out) {
  __shared__ __align__(16) u16 Xs[64 * 64];          // 8 KB : 512 granules, K-major
  __shared__ __align__(16) u16 Wslab[3 * 128 * 64];  // 48 KB: 3072 granules, K-major
  const u16* wih_b = wcat + 131072;   // [768,512]
  const u16* whh_b = wcat + 524288;   // [768,256]
  int m0 = blockIdx.x * 64;
  int j0 = blockIdx.y * 128;
  int t = threadIdx.x, w = t >> 6, lane = t & 63;
  int cpar = lane >> 5;
  // staging source bases (per-lane row pointers); W row-parity (j&1)==(w&1) folds into base
  const u16* bxi = inp + (size_t)(m0 + lane) * 512;
  const u16* bxh = h   + (size_t)(m0 + lane) * 256;
  const u16* bwi = wih_b + (size_t)(j0 + (w & 1) * 64 + lane) * 512;
  const u16* bwh = whh_b + (size_t)(j0 + (w & 1) * 64 + lane) * 256;
  // compute-phase per-lane LDS byte bases
  int BX = cpar * 1024 + (lane & 31) * 16;            // + ks*2048 (+512 for af1)
  int BW = cpar * 2048 + (32 * w + (lane & 31)) * 16; // + s*16384 + ks*4096

  f32x16 acc[4][2];
#pragma unroll
  for (int g = 0; g < 4; ++g)
#pragma unroll
    for (int mt = 0; mt < 2; ++mt) acc[g][mt] = (f32x16)0.0f;

#pragma unroll 1
  for (int kt = 0; kt < 12; ++kt) {
    bool lo = (kt < 8);
    int k0 = lo ? kt * 64 : (kt - 8) * 64;
    // ---- stage: 8 X calls (i 0..1) + 48 W calls (i 2..13), og = i*4 + w ----
    {
      const u16* xb = (lo ? bxi : bxh) + k0;
#pragma unroll
      for (int i = 0; i < 2; ++i) {
        int og = i * 4 + w;                 // 0..7 -> kc
        async16(xb + og * 8, &Xs[og * 512]);
      }
      if (lo) {
#pragma unroll
        for (int i = 2; i < 14; ++i) {
          int j = i * 4 + w - 8;            // 0..47
          int s = j >> 4, kc = (j >> 1) & 7;
          async16(bwi + s * 131072 + k0 + kc * 8, &Wslab[j * 512]);
        }
      } else {
#pragma unroll
        for (int i = 2; i < 14; ++i) {
          int j = i * 4 + w - 8;
          int s = j >> 4, kc = (j >> 1) & 7;
          async16(bwh + s * 65536 + k0 + kc * 8, &Wslab[j * 512]);
        }
      }
    }
    __syncthreads();
    // ---- compute: all addresses = base + compile-time immediate ----
    if (lo) {                               // gi phase: slab2 -> acc[2] (i_n)
#pragma unroll
      for (int ks = 0; ks < 4; ++ks) {
        bf16x8 af0 = *(const bf16x8*)((const char*)Xs + BX + ks * 2048);
        bf16x8 af1 = *(const bf16x8*)((const char*)Xs + BX + ks * 2048 + 512);
        bf16x8 b0 = *(const bf16x8*)((const char*)Wslab + BW + ks * 4096);
        bf16x8 b1 = *(const bf16x8*)((const char*)Wslab + BW + 16384 + ks * 4096);
        bf16x8 b2 = *(const bf16x8*)((const char*)Wslab + BW + 32768 + ks * 4096);
        acc[0][0] = __builtin_amdgcn_mfma_f32_32x32x16_bf16(af0, b0, acc[0][0], 0, 0, 0);
        acc[0][1] = __builtin_amdgcn_mfma_f32_32x32x16_bf16(af1, b0, acc[0][1], 0, 0, 0);
        acc[1][0] = __builtin_amdgcn_mfma_f32_32x32x16_bf16(af0, b1, acc[1][0], 0, 0, 0);
        acc[1][1] = __builtin_amdgcn_mfma_f32_32x32x16_bf16(af1, b1, acc[1][1], 0, 0, 0);
        acc[2][0] = __builtin_amdgcn_mfma_f32_32x32x16_bf16(af0, b2, acc[2][0], 0, 0, 0);
        acc[2][1] = __builtin_amdgcn_mfma_f32_32x32x16_bf16(af1, b2, acc[2][1], 0, 0, 0);
      }
    } else {                                // gh phase: slab2 -> acc[3] (h_n)
#pragma unroll
      for (int ks = 0; ks < 4; ++ks) {
        bf16x8 af0 = *(const bf16x8*)((const char*)Xs + BX + ks * 2048);
        bf16x8 af1 = *(const bf16x8*)((const char*)Xs + BX + ks * 2048 + 512);
        bf16x8 b0 = *(const bf16x8*)((const char*)Wslab + BW + ks * 4096);
        bf16x8 b1 = *(const bf16x8*)((const char*)Wslab + BW + 16384 + ks * 4096);
        bf16x8 b2 = *(const bf16x8*)((const char*)Wslab + BW + 32768 + ks * 4096);
        acc[0][0] = __builtin_amdgcn_mfma_f32_32x32x16_bf16(af0, b0, acc[0][0], 0, 0, 0);
        acc[0][1] = __builtin_amdgcn_mfma_f32_32x32x16_bf16(af1, b0, acc[0][1], 0, 0, 0);
        acc[1][0] = __builtin_amdgcn_mfma_f32_32x32x16_bf16(af0, b1, acc[1][0], 0, 0, 0);
        acc[1][1] = __builtin_amdgcn_mfma_f32_32x32x16_bf16(af1, b1, acc[1][1], 0, 0, 0);
        acc[3][0] = __builtin_amdgcn_mfma_f32_32x32x16_bf16(af0, b2, acc[3][0], 0, 0, 0);
        acc[3][1] = __builtin_amdgcn_mfma_f32_32x32x16_bf16(af1, b2, acc[3][1], 0, 0, 0);
      }
    }
    __syncthreads();
  }
  // epilogue (identical to round-0): stage h tile [64][128] into Wslab slab 2
  u16* Hh = Wslab + 2 * 8192;
  {
    int rsub4 = lane >> 4, cch = lane & 15;
#pragma unroll
    for (int i = 0; i < 4; ++i) {
      int og = i * 4 + w, r0 = og * 4;
      int kofsH = ((cch ^ ((r0 & 4) | rsub4)) << 3);
      async16(h + (size_t)(m0 + r0 + rsub4) * 256 + j0 + kofsH, &Hh[r0 * 128]);
    }
  }
  __syncthreads();
  // gates in-register; hv from Hh; hy -> F f32[64][128] (aliases Wslab slabs 0-1)
  float* F = (float*)Wslab;
  int jl = 32 * w + (lane & 31);
  int j = j0 + jl;
  float brs = b_ih[j] + b_hh[j];
  float bis = b_ih[256 + j] + b_hh[256 + j];
  float bin = b_ih[512 + j];
  float bhn = b_hh[512 + j];
  int jc = jl >> 3, je = (jl & 7) * 2;
#pragma unroll
  for (int mt = 0; mt < 2; ++mt) {
#pragma unroll
    for (int e = 0; e < 16; ++e) {
      int row = (e & 3) + 8 * (e >> 2) + 4 * (lane >> 5);
      int mloc = 32 * mt + row;
      float r  = sigmoidf_(acc[0][mt][e] + brs);
      float ig = sigmoidf_(acc[1][mt][e] + bis);
      float hn = acc[3][mt][e] + bhn;
      float ng = tanhf_(acc[2][mt][e] + bin + r * hn);
      float hv = bf2f(*(const u16*)((char*)Hh + mloc * 256 + ((jc ^ (mloc & 7)) << 4) + je));
      F[mloc * 128 + jl] = ng + ig * (hv - ng);
    }
  }
  __syncthreads();
  for (int it = 0; it < 16; ++it) {
    int id = it * 256 + t;            // [64 m][64 j-pairs]
    int mloc = id >> 6, jp = (id & 63) * 2;
    float2 v = *(const float2*)(F + mloc * 128 + jp);
    *(float2*)(out + (size_t)(m0 + mloc) * 256 + j0 + jp) = v;
  }
}

extern "C" void kernel_launch(void* const* d_in, const int* in_sizes, int n_in,
                              void* d_out, int out_size, void* d_ws, size_t ws_size,
                              hipStream_t stream) {
  (void)in_sizes; (void)n_in; (void)out_size; (void)ws_size;
  const int*   inputs = (const int*)d_in[0];
  const float* A      = (const float*)d_in[1];
  const float* emb    = (const float*)d_in[2];
  const float* W_in   = (const float*)d_in[3];
  const float* b_in   = (const float*)d_in[4];
  const float* W_out  = (const float*)d_in[5];
  const float* b_out  = (const float*)d_in[6];
  const float* w_ih   = (const float*)d_in[7];
  const float* b_ih   = (const float*)d_in[8];
  const float* w_hh   = (const float*)d_in[9];
  const float* b_hh   = (const float*)d_in[10];
  const float* b_iah  = (const float*)d_in[11];
  const float* b_oah  = (const float*)d_in[12];
  float* out = (float*)d_out;

  u16* h    = (u16*)d_ws;                 // BN*256 bf16 = 16.8 MB
  u16* HioT = h + (size_t)BN_ * HHH;      // 33.6 MB
  u16* inp  = HioT + (size_t)BN_ * H2_;   // 33.6 MB
  u16* wcat = inp + (size_t)BN_ * H2_;    // 1.44 MB

  k_convert<<<2816, 256, 0, stream>>>(W_in, W_out, w_ih, w_hh, wcat);
  k_gather_norm<<<BN_ / 4, 256, 0, stream>>>(inputs, emb, h);
  k_hio<<<dim3(BN_ / 128, 4), 256, 0, stream>>>(h, wcat, b_in, b_out, HioT);
  k_amul<<<BB, 256, 0, stream>>>(A, HioT, b_iah, b_oah, inp);
  k_gates<<<dim3(BN_ / 64, 2), 256, 0, stream>>>(inp, h, wcat, b_ih, b_hh, out);
}

// Round 4
// 415.963 us; speedup vs baseline: 1.1043x; 1.0476x over previous
//
#include <hip/hip_runtime.h>
#include <stdint.h>

// Problem dims
#define BB   512
#define NNN  64
#define HHH  256
#define BN_  32768   // B*N
#define H2_  512
#define H3_  768

typedef unsigned short u16;
typedef unsigned int   u32;
typedef __attribute__((ext_vector_type(8)))  short bf16x8;   // 8 bf16 in 4 VGPRs
typedef __attribute__((ext_vector_type(4)))  float f32x4;
typedef __attribute__((ext_vector_type(16))) float f32x16;

__device__ __forceinline__ u16 f2bf(float f) {
  union { float f; u32 u; } x; x.f = f;
  return (u16)((x.u + 0x7fffu + ((x.u >> 16) & 1u)) >> 16);  // RNE
}
__device__ __forceinline__ float bf2f(u16 v) {
  union { u32 u; float f; } x; x.u = ((u32)v) << 16; return x.f;
}
__device__ __forceinline__ void async16(const void* g, void* l) {
  __builtin_amdgcn_global_load_lds(
      (const __attribute__((address_space(1))) u32*)(uintptr_t)g,
      (__attribute__((address_space(3))) u32*)(uintptr_t)l, 16, 0, 0);
}
__device__ __forceinline__ float sigmoidf_(float x) { return 1.0f / (1.0f + __expf(-x)); }
__device__ __forceinline__ float tanhf_(float x)    { return 2.0f / (1.0f + __expf(-2.0f * x)) - 1.0f; }

// ---------------------------------------------------------------- K0: f32 weights -> bf16 wcat
// wcat layout (elems): [W_in 65536 | W_out 65536 | w_ih 393216 | w_hh 196608]
__global__ __launch_bounds__(256) void k_convert(const float* __restrict__ W_in,
                                                 const float* __restrict__ W_out,
                                                 const float* __restrict__ w_ih,
                                                 const float* __restrict__ w_hh,
                                                 u16* __restrict__ wcat) {
  int i = blockIdx.x * 256 + threadIdx.x;
  const float* src; int off;
  if (i < 65536)       { src = W_in;  off = i; }
  else if (i < 131072) { src = W_out; off = i - 65536; }
  else if (i < 524288) { src = w_ih;  off = i - 131072; }
  else                 { src = w_hh;  off = i - 524288; }
  wcat[i] = f2bf(src[off]);
}

// ---------------------------------------------------------------- K1: gather + L2 norm
__global__ __launch_bounds__(256) void k_gather_norm(const int* __restrict__ idx,
                                                     const float* __restrict__ emb,
                                                     u16* __restrict__ h) {
  int row  = blockIdx.x * 4 + (threadIdx.x >> 6);
  int lane = threadIdx.x & 63;
  int e = idx[row];
  float4 v = *(const float4*)(emb + (size_t)e * HHH + lane * 4);
  float s = v.x * v.x + v.y * v.y + v.z * v.z + v.w * v.w;
  for (int off = 32; off; off >>= 1) s += __shfl_xor(s, off, 64);
  float sc = 1.0f / (sqrtf(s) + 1e-12f);
  ushort4 o;
  o.x = f2bf(v.x * sc); o.y = f2bf(v.y * sc); o.z = f2bf(v.z * sc); o.w = f2bf(v.w * sc);
  *(ushort4*)(h + (size_t)row * HHH + lane * 4) = o;
}

// ---------------------------------------------------------------- K2: HioT = wcat @ h^T (+bias)
// A-op = h node rows (M), B-op = wcat channel rows (N) -> C[node][ch]; epilogue transposes
// through LDS so HBM stores are 16B/lane coalesced. HioT[b][c][node64].
__global__ __launch_bounds__(256) void k_hio(const u16* __restrict__ h,
                                             const u16* __restrict__ wcat,
                                             const float* __restrict__ b_in,
                                             const float* __restrict__ b_out,
                                             u16* __restrict__ HioT) {
  __shared__ __align__(16) char smem[34816];         // phase1: Ws 16K | Hs 16K ; phase2: Tt [128][136] u16
  u16* Ws = (u16*)smem;
  u16* Hs = Ws + 8192;
  u16* Tt = (u16*)smem;
  int c0 = blockIdx.y * 128;
  int n0 = blockIdx.x * 128;
  int t = threadIdx.x, w = t >> 6, lane = t & 63;
  int wm = w >> 1, wn = w & 1;    // wm: node half, wn: channel half
  int rsub = lane >> 3, kofs = ((lane & 7) ^ rsub) << 3;
  const u16* wbase = wcat + (size_t)c0 * 256;
  f32x4 acc[4][4];   // [node-tile][ch-tile]
  for (int a = 0; a < 4; ++a) for (int b = 0; b < 4; ++b) acc[a][b] = (f32x4)0.0f;

  for (int kt = 0; kt < 4; ++kt) {
    int k0 = kt * 64;
    for (int i = 0; i < 4; ++i) {
      int r = 32 * w + 8 * i;
      async16(wbase + (size_t)(r + rsub) * 256 + k0 + kofs, &Ws[r * 64]);
      async16(h + (size_t)(n0 + r + rsub) * 256 + k0 + kofs, &Hs[r * 64]);
    }
    __syncthreads();
    for (int ks = 0; ks < 2; ++ks) {
      int c = ks * 4 + (lane >> 4);
      bf16x8 af[4], bf[4];
      for (int mt = 0; mt < 4; ++mt) {
        int r = 64 * wm + 16 * mt + (lane & 15);
        af[mt] = *(const bf16x8*)(Hs + r * 64 + ((c ^ (r & 7)) << 3));
      }
      for (int nt = 0; nt < 4; ++nt) {
        int r = 64 * wn + 16 * nt + (lane & 15);
        bf[nt] = *(const bf16x8*)(Ws + r * 64 + ((c ^ (r & 7)) << 3));
      }
      for (int mt = 0; mt < 4; ++mt)
        for (int nt = 0; nt < 4; ++nt)
          acc[mt][nt] = __builtin_amdgcn_mfma_f32_16x16x32_bf16(af[mt], bf[nt], acc[mt][nt], 0, 0, 0);
    }
    __syncthreads();
  }
  // epilogue: bias + pack 4 consecutive nodes per b64 into Tt[ch][node(pad 136)]
  for (int nt = 0; nt < 4; ++nt) {
    int chl = 64 * wn + 16 * nt + (lane & 15);
    int cg = c0 + chl;
    float bv = (cg < 256) ? b_in[cg] : b_out[cg - 256];
    for (int mt = 0; mt < 4; ++mt) {
      int nb = 64 * wm + 16 * mt + (lane >> 4) * 4;
      u32 lo = (u32)f2bf(acc[mt][nt][0] + bv) | ((u32)f2bf(acc[mt][nt][1] + bv) << 16);
      u32 hi = (u32)f2bf(acc[mt][nt][2] + bv) | ((u32)f2bf(acc[mt][nt][3] + bv) << 16);
      *(uint2*)(Tt + chl * 136 + nb) = make_uint2(lo, hi);
    }
  }
  __syncthreads();
  // coalesced store: 8 iters, 16B per thread
  for (int it = 0; it < 8; ++it) {
    int id = it * 256 + t;                 // [128 ch][2 nblk][8 chunk]
    int ch = id >> 4, nb = (id >> 3) & 1, c8 = id & 7;
    uint4 v = *(const uint4*)(Tt + ch * 136 + nb * 64 + c8 * 8);
    *(uint4*)(HioT + (size_t)((n0 >> 6) + nb) * 32768 + (size_t)(c0 + ch) * 64 + c8 * 8) = v;
  }
}

// ---------------------------------------------------------------- K3: per-batch adjacency matmul
// A-op = HioT channel rows (M), B-op = A node rows (N) -> C[ch][node]; reg-quads pack 4
// consecutive ch -> LDS transpose -> coalesced 16B stores of inp[node][ch].
__global__ __launch_bounds__(256) void k_amul(const float* __restrict__ Ag,
                                              const u16* __restrict__ HioT,
                                              const float* __restrict__ b_iah,
                                              const float* __restrict__ b_oah,
                                              u16* __restrict__ inp) {
  __shared__ __align__(16) u16 As[64 * 136];   // A[b]: 64 x 128 bf16, pad->136
  __shared__ __align__(16) u16 Hs[256 * 64];   // phase: HioT half (swz) ; then Tt2 [64 node][256 ch] xor16B
  int b = blockIdx.x;
  int t = threadIdx.x, w = t >> 6, lane = t & 63;
  int rsub = lane >> 3, kofs = ((lane & 7) ^ rsub) << 3;
  {
    int r = t >> 2, q = t & 3;
    const float4* src = (const float4*)(Ag + (size_t)b * 8192 + r * 128 + q * 32);
    u16* dst = As + r * 136 + q * 32;
    for (int j = 0; j < 8; ++j) {
      float4 v = src[j];
      ushort4 o;
      o.x = f2bf(v.x); o.y = f2bf(v.y); o.z = f2bf(v.z); o.w = f2bf(v.w);
      *(ushort4*)(dst + j * 4) = o;
    }
  }
  for (int co = 0; co < 2; ++co) {
    __syncthreads();
    for (int i = 0; i < 2; ++i) {
      int rb = 64 * w + 32 * i;
      for (int s = 0; s < 4; ++s)
        async16(HioT + (size_t)b * 32768 + (size_t)(co * 256 + rb + 8 * s + rsub) * 64 + kofs,
                &Hs[(rb + 8 * s) * 64]);
    }
    __syncthreads();
    f32x4 acc[4][4];   // [ch-tile][node-tile]
    for (int a = 0; a < 4; ++a) for (int c = 0; c < 4; ++c) acc[a][c] = (f32x4)0.0f;
    for (int ks = 0; ks < 2; ++ks) {
      int c = ks * 4 + (lane >> 4);            // node-chunk
      int kk = co * 64 + ks * 32 + (lane >> 4) * 8;
      bf16x8 af[4], bf[4];
      for (int mt = 0; mt < 4; ++mt) {
        int r = 64 * w + 16 * mt + (lane & 15);   // ch row (within 256-half)
        af[mt] = *(const bf16x8*)(Hs + r * 64 + ((c ^ (r & 7)) << 3));
      }
      for (int nt = 0; nt < 4; ++nt) {
        int n = 16 * nt + (lane & 15);
        bf[nt] = *(const bf16x8*)(As + n * 136 + kk);
      }
      for (int mt = 0; mt < 4; ++mt)
        for (int nt = 0; nt < 4; ++nt)
          acc[mt][nt] = __builtin_amdgcn_mfma_f32_16x16x32_bf16(af[mt], bf[nt], acc[mt][nt], 0, 0, 0);
    }
    __syncthreads();   // done reading Hs; reuse as Tt2
    const float* bias = (co == 0) ? b_iah : b_oah;
    u16* Tt2 = Hs;     // [64 node][256 ch], 16B-chunk xor swizzle by (node&7)
    for (int mt = 0; mt < 4; ++mt) {
      int chb = 64 * w + 16 * mt + (lane >> 4) * 4;
      float b0 = bias[chb], b1 = bias[chb + 1], b2 = bias[chb + 2], b3 = bias[chb + 3];
      for (int nt = 0; nt < 4; ++nt) {
        int node = 16 * nt + (lane & 15);
        u32 lo = (u32)f2bf(acc[mt][nt][0] + b0) | ((u32)f2bf(acc[mt][nt][1] + b1) << 16);
        u32 hi = (u32)f2bf(acc[mt][nt][2] + b2) | ((u32)f2bf(acc[mt][nt][3] + b3) << 16);
        int byte = node * 512 + (((chb >> 3) ^ (node & 7)) << 4) + (chb & 7) * 2;
        *(uint2*)((char*)Tt2 + byte) = make_uint2(lo, hi);
      }
    }
    __syncthreads();
    for (int it = 0; it < 8; ++it) {
      int id = it * 256 + t;                 // [64 node][32 chunk16B]
      int node = id >> 5, c = id & 31;
      uint4 v = *(const uint4*)((char*)Tt2 + node * 512 + ((c ^ (node & 7)) << 4));
      *(uint4*)(inp + ((size_t)b * 64 + node) * 512 + co * 256 + c * 8) = v;
    }
  }
}

// ---------------------------------------------------------------- K4: fused gate GEMM + GRU (32x32x16)
// v5 = v4 (K-major linear LDS granules, zero bank conflicts, base+imm addressing) + schedule
// pinning: sched_barrier(0) at the end of EACH ks-iteration body. v4's spill (460MB scratch
// writes) came from the scheduler hoisting all 20 ds_read_b128 results of the 4 unrolled ks
// iterations (80 VGPRs) above the MFMAs -- possible precisely BECAUSE base+imm addressing
// removed every dependency. The fence caps load liveness at one ks group (20 VGPRs); LDS
// latency is hidden by the 8 waves/CU (2 blocks x 4 waves), as in round-0's spill-free run.
__global__ __launch_bounds__(256, 2) void k_gates(const u16* __restrict__ inp,
                                                  const u16* __restrict__ h,
                                                  const u16* __restrict__ wcat,
                                                  const float* __restrict__ b_ih,
                                                  const float* __restrict__ b_hh,
                                                  float* __restrict__ out) {
  __shared__ __align__(16) u16 Xs[64 * 64];          // 8 KB : 512 granules, K-major
  __shared__ __align__(16) u16 Wslab[3 * 128 * 64];  // 48 KB: 3072 granules, K-major
  const u16* wih_b = wcat + 131072;   // [768,512]
  const u16* whh_b = wcat + 524288;   // [768,256]
  int m0 = blockIdx.x * 64;
  int j0 = blockIdx.y * 128;
  int t = threadIdx.x, w = t >> 6, lane = t & 63;
  int cpar = lane >> 5;
  // staging source bases (per-lane row pointers); W row-parity (j&1)==(w&1) folds into base
  const u16* bxi = inp + (size_t)(m0 + lane) * 512;
  const u16* bxh = h   + (size_t)(m0 + lane) * 256;
  const u16* bwi = wih_b + (size_t)(j0 + (w & 1) * 64 + lane) * 512;
  const u16* bwh = whh_b + (size_t)(j0 + (w & 1) * 64 + lane) * 256;
  // compute-phase per-lane LDS byte bases
  int BX = cpar * 1024 + (lane & 31) * 16;            // + ks*2048 (+512 for af1)
  int BW = cpar * 2048 + (32 * w + (lane & 31)) * 16; // + s*16384 + ks*4096

  f32x16 acc[4][2];
#pragma unroll
  for (int g = 0; g < 4; ++g)
#pragma unroll
    for (int mt = 0; mt < 2; ++mt) acc[g][mt] = (f32x16)0.0f;

#pragma unroll 1
  for (int kt = 0; kt < 12; ++kt) {
    bool lo = (kt < 8);
    int k0 = lo ? kt * 64 : (kt - 8) * 64;
    // ---- stage: 8 X calls (i 0..1) + 48 W calls (i 2..13), og = i*4 + w ----
    {
      const u16* xb = (lo ? bxi : bxh) + k0;
#pragma unroll
      for (int i = 0; i < 2; ++i) {
        int og = i * 4 + w;                 // 0..7 -> kc
        async16(xb + og * 8, &Xs[og * 512]);
      }
      if (lo) {
#pragma unroll
        for (int i = 2; i < 14; ++i) {
          int j = i * 4 + w - 8;            // 0..47
          int s = j >> 4, kc = (j >> 1) & 7;
          async16(bwi + s * 131072 + k0 + kc * 8, &Wslab[j * 512]);
        }
      } else {
#pragma unroll
        for (int i = 2; i < 14; ++i) {
          int j = i * 4 + w - 8;
          int s = j >> 4, kc = (j >> 1) & 7;
          async16(bwh + s * 65536 + k0 + kc * 8, &Wslab[j * 512]);
        }
      }
    }
    __syncthreads();
    // ---- compute: all addresses = base + compile-time immediate; sched_barrier(0) per ks
    // group caps ds_read liveness at 20 VGPRs (anti-spill) ----
    if (lo) {                               // gi phase: slab2 -> acc[2] (i_n)
#pragma unroll
      for (int ks = 0; ks < 4; ++ks) {
        bf16x8 af0 = *(const bf16x8*)((const char*)Xs + BX + ks * 2048);
        bf16x8 af1 = *(const bf16x8*)((const char*)Xs + BX + ks * 2048 + 512);
        bf16x8 b0 = *(const bf16x8*)((const char*)Wslab + BW + ks * 4096);
        bf16x8 b1 = *(const bf16x8*)((const char*)Wslab + BW + 16384 + ks * 4096);
        bf16x8 b2 = *(const bf16x8*)((const char*)Wslab + BW + 32768 + ks * 4096);
        acc[0][0] = __builtin_amdgcn_mfma_f32_32x32x16_bf16(af0, b0, acc[0][0], 0, 0, 0);
        acc[0][1] = __builtin_amdgcn_mfma_f32_32x32x16_bf16(af1, b0, acc[0][1], 0, 0, 0);
        acc[1][0] = __builtin_amdgcn_mfma_f32_32x32x16_bf16(af0, b1, acc[1][0], 0, 0, 0);
        acc[1][1] = __builtin_amdgcn_mfma_f32_32x32x16_bf16(af1, b1, acc[1][1], 0, 0, 0);
        acc[2][0] = __builtin_amdgcn_mfma_f32_32x32x16_bf16(af0, b2, acc[2][0], 0, 0, 0);
        acc[2][1] = __builtin_amdgcn_mfma_f32_32x32x16_bf16(af1, b2, acc[2][1], 0, 0, 0);
        __builtin_amdgcn_sched_barrier(0);
      }
    } else {                                // gh phase: slab2 -> acc[3] (h_n)
#pragma unroll
      for (int ks = 0; ks < 4; ++ks) {
        bf16x8 af0 = *(const bf16x8*)((const char*)Xs + BX + ks * 2048);
        bf16x8 af1 = *(const bf16x8*)((const char*)Xs + BX + ks * 2048 + 512);
        bf16x8 b0 = *(const bf16x8*)((const char*)Wslab + BW + ks * 4096);
        bf16x8 b1 = *(const bf16x8*)((const char*)Wslab + BW + 16384 + ks * 4096);
        bf16x8 b2 = *(const bf16x8*)((const char*)Wslab + BW + 32768 + ks * 4096);
        acc[0][0] = __builtin_amdgcn_mfma_f32_32x32x16_bf16(af0, b0, acc[0][0], 0, 0, 0);
        acc[0][1] = __builtin_amdgcn_mfma_f32_32x32x16_bf16(af1, b0, acc[0][1], 0, 0, 0);
        acc[1][0] = __builtin_amdgcn_mfma_f32_32x32x16_bf16(af0, b1, acc[1][0], 0, 0, 0);
        acc[1][1] = __builtin_amdgcn_mfma_f32_32x32x16_bf16(af1, b1, acc[1][1], 0, 0, 0);
        acc[3][0] = __builtin_amdgcn_mfma_f32_32x32x16_bf16(af0, b2, acc[3][0], 0, 0, 0);
        acc[3][1] = __builtin_amdgcn_mfma_f32_32x32x16_bf16(af1, b2, acc[3][1], 0, 0, 0);
        __builtin_amdgcn_sched_barrier(0);
      }
    }
    __syncthreads();
  }
  // epilogue (identical to round-0): stage h tile [64][128] into Wslab slab 2
  u16* Hh = Wslab + 2 * 8192;
  {
    int rsub4 = lane >> 4, cch = lane & 15;
#pragma unroll
    for (int i = 0; i < 4; ++i) {
      int og = i * 4 + w, r0 = og * 4;
      int kofsH = ((cch ^ ((r0 & 4) | rsub4)) << 3);
      async16(h + (size_t)(m0 + r0 + rsub4) * 256 + j0 + kofsH, &Hh[r0 * 128]);
    }
  }
  __syncthreads();
  // gates in-register; hv from Hh; hy -> F f32[64][128] (aliases Wslab slabs 0-1)
  float* F = (float*)Wslab;
  int jl = 32 * w + (lane & 31);
  int j = j0 + jl;
  float brs = b_ih[j] + b_hh[j];
  float bis = b_ih[256 + j] + b_hh[256 + j];
  float bin = b_ih[512 + j];
  float bhn = b_hh[512 + j];
  int jc = jl >> 3, je = (jl & 7) * 2;
#pragma unroll
  for (int mt = 0; mt < 2; ++mt) {
#pragma unroll
    for (int e = 0; e < 16; ++e) {
      int row = (e & 3) + 8 * (e >> 2) + 4 * (lane >> 5);
      int mloc = 32 * mt + row;
      float r  = sigmoidf_(acc[0][mt][e] + brs);
      float ig = sigmoidf_(acc[1][mt][e] + bis);
      float hn = acc[3][mt][e] + bhn;
      float ng = tanhf_(acc[2][mt][e] + bin + r * hn);
      float hv = bf2f(*(const u16*)((char*)Hh + mloc * 256 + ((jc ^ (mloc & 7)) << 4) + je));
      F[mloc * 128 + jl] = ng + ig * (hv - ng);
    }
  }
  __syncthreads();
  for (int it = 0; it < 16; ++it) {
    int id = it * 256 + t;            // [64 m][64 j-pairs]
    int mloc = id >> 6, jp = (id & 63) * 2;
    float2 v = *(const float2*)(F + mloc * 128 + jp);
    *(float2*)(out + (size_t)(m0 + mloc) * 256 + j0 + jp) = v;
  }
}

extern "C" void kernel_launch(void* const* d_in, const int* in_sizes, int n_in,
                              void* d_out, int out_size, void* d_ws, size_t ws_size,
                              hipStream_t stream) {
  (void)in_sizes; (void)n_in; (void)out_size; (void)ws_size;
  const int*   inputs = (const int*)d_in[0];
  const float* A      = (const float*)d_in[1];
  const float* emb    = (const float*)d_in[2];
  const float* W_in   = (const float*)d_in[3];
  const float* b_in   = (const float*)d_in[4];
  const float* W_out  = (const float*)d_in[5];
  const float* b_out  = (const float*)d_in[6];
  const float* w_ih   = (const float*)d_in[7];
  const float* b_ih   = (const float*)d_in[8];
  const float* w_hh   = (const float*)d_in[9];
  const float* b_hh   = (const float*)d_in[10];
  const float* b_iah  = (const float*)d_in[11];
  const float* b_oah  = (const float*)d_in[12];
  float* out = (float*)d_out;

  u16* h    = (u16*)d_ws;                 // BN*256 bf16 = 16.8 MB
  u16* HioT = h + (size_t)BN_ * HHH;      // 33.6 MB
  u16* inp  = HioT + (size_t)BN_ * H2_;   // 33.6 MB
  u16* wcat = inp + (size_t)BN_ * H2_;    // 1.44 MB

  k_convert<<<2816, 256, 0, stream>>>(W_in, W_out, w_ih, w_hh, wcat);
  k_gather_norm<<<BN_ / 4, 256, 0, stream>>>(inputs, emb, h);
  k_hio<<<dim3(BN_ / 128, 4), 256, 0, stream>>>(h, wcat, b_in, b_out, HioT);
  k_amul<<<BB, 256, 0, stream>>>(A, HioT, b_iah, b_oah, inp);
  k_gates<<<dim3(BN_ / 64, 2), 256, 0, stream>>>(inp, h, wcat, b_ih, b_hh, out);
}

// Round 6
// 281.306 us; speedup vs baseline: 1.6329x; 1.4787x over previous
//
#include <hip/hip_runtime.h>
#include <stdint.h>

// Problem dims
#define BB   512
#define NNN  64
#define HHH  256
#define BN_  32768   // B*N
#define H2_  512
#define H3_  768

typedef unsigned short u16;
typedef unsigned int   u32;
typedef __attribute__((ext_vector_type(8)))  short bf16x8;   // 8 bf16 in 4 VGPRs
typedef __attribute__((ext_vector_type(4)))  float f32x4;
typedef __attribute__((ext_vector_type(16))) float f32x16;

__device__ __forceinline__ u16 f2bf(float f) {
  union { float f; u32 u; } x; x.f = f;
  return (u16)((x.u + 0x7fffu + ((x.u >> 16) & 1u)) >> 16);  // RNE
}
__device__ __forceinline__ float bf2f(u16 v) {
  union { u32 u; float f; } x; x.u = ((u32)v) << 16; return x.f;
}
__device__ __forceinline__ void async16(const void* g, void* l) {
  __builtin_amdgcn_global_load_lds(
      (const __attribute__((address_space(1))) u32*)(uintptr_t)g,
      (__attribute__((address_space(3))) u32*)(uintptr_t)l, 16, 0, 0);
}
__device__ __forceinline__ float sigmoidf_(float x) { return 1.0f / (1.0f + __expf(-x)); }
__device__ __forceinline__ float tanhf_(float x)    { return 2.0f / (1.0f + __expf(-2.0f * x)) - 1.0f; }

// ---------------------------------------------------------------- K0: f32 weights -> bf16 wcat
// wcat layout (elems): [W_in 65536 | W_out 65536 | w_ih 393216 | w_hh 196608]
__global__ __launch_bounds__(256) void k_convert(const float* __restrict__ W_in,
                                                 const float* __restrict__ W_out,
                                                 const float* __restrict__ w_ih,
                                                 const float* __restrict__ w_hh,
                                                 u16* __restrict__ wcat) {
  int i = blockIdx.x * 256 + threadIdx.x;
  const float* src; int off;
  if (i < 65536)       { src = W_in;  off = i; }
  else if (i < 131072) { src = W_out; off = i - 65536; }
  else if (i < 524288) { src = w_ih;  off = i - 131072; }
  else                 { src = w_hh;  off = i - 524288; }
  wcat[i] = f2bf(src[off]);
}

// ---------------------------------------------------------------- K1: gather + L2 norm
__global__ __launch_bounds__(256) void k_gather_norm(const int* __restrict__ idx,
                                                     const float* __restrict__ emb,
                                                     u16* __restrict__ h) {
  int row  = blockIdx.x * 4 + (threadIdx.x >> 6);
  int lane = threadIdx.x & 63;
  int e = idx[row];
  float4 v = *(const float4*)(emb + (size_t)e * HHH + lane * 4);
  float s = v.x * v.x + v.y * v.y + v.z * v.z + v.w * v.w;
  for (int off = 32; off; off >>= 1) s += __shfl_xor(s, off, 64);
  float sc = 1.0f / (sqrtf(s) + 1e-12f);
  ushort4 o;
  o.x = f2bf(v.x * sc); o.y = f2bf(v.y * sc); o.z = f2bf(v.z * sc); o.w = f2bf(v.w * sc);
  *(ushort4*)(h + (size_t)row * HHH + lane * 4) = o;
}

// ---------------------------------------------------------------- K2: HioT = wcat @ h^T (+bias)
// A-op = h node rows (M), B-op = wcat channel rows (N) -> C[node][ch]; epilogue transposes
// through LDS so HBM stores are 16B/lane coalesced. HioT[b][c][node64].
__global__ __launch_bounds__(256) void k_hio(const u16* __restrict__ h,
                                             const u16* __restrict__ wcat,
                                             const float* __restrict__ b_in,
                                             const float* __restrict__ b_out,
                                             u16* __restrict__ HioT) {
  __shared__ __align__(16) char smem[34816];         // phase1: Ws 16K | Hs 16K ; phase2: Tt [128][136] u16
  u16* Ws = (u16*)smem;
  u16* Hs = Ws + 8192;
  u16* Tt = (u16*)smem;
  int c0 = blockIdx.y * 128;
  int n0 = blockIdx.x * 128;
  int t = threadIdx.x, w = t >> 6, lane = t & 63;
  int wm = w >> 1, wn = w & 1;    // wm: node half, wn: channel half
  int rsub = lane >> 3, kofs = ((lane & 7) ^ rsub) << 3;
  const u16* wbase = wcat + (size_t)c0 * 256;
  f32x4 acc[4][4];   // [node-tile][ch-tile]
  for (int a = 0; a < 4; ++a) for (int b = 0; b < 4; ++b) acc[a][b] = (f32x4)0.0f;

  for (int kt = 0; kt < 4; ++kt) {
    int k0 = kt * 64;
    for (int i = 0; i < 4; ++i) {
      int r = 32 * w + 8 * i;
      async16(wbase + (size_t)(r + rsub) * 256 + k0 + kofs, &Ws[r * 64]);
      async16(h + (size_t)(n0 + r + rsub) * 256 + k0 + kofs, &Hs[r * 64]);
    }
    __syncthreads();
    for (int ks = 0; ks < 2; ++ks) {
      int c = ks * 4 + (lane >> 4);
      bf16x8 af[4], bf[4];
      for (int mt = 0; mt < 4; ++mt) {
        int r = 64 * wm + 16 * mt + (lane & 15);
        af[mt] = *(const bf16x8*)(Hs + r * 64 + ((c ^ (r & 7)) << 3));
      }
      for (int nt = 0; nt < 4; ++nt) {
        int r = 64 * wn + 16 * nt + (lane & 15);
        bf[nt] = *(const bf16x8*)(Ws + r * 64 + ((c ^ (r & 7)) << 3));
      }
      for (int mt = 0; mt < 4; ++mt)
        for (int nt = 0; nt < 4; ++nt)
          acc[mt][nt] = __builtin_amdgcn_mfma_f32_16x16x32_bf16(af[mt], bf[nt], acc[mt][nt], 0, 0, 0);
    }
    __syncthreads();
  }
  // epilogue: bias + pack 4 consecutive nodes per b64 into Tt[ch][node(pad 136)]
  for (int nt = 0; nt < 4; ++nt) {
    int chl = 64 * wn + 16 * nt + (lane & 15);
    int cg = c0 + chl;
    float bv = (cg < 256) ? b_in[cg] : b_out[cg - 256];
    for (int mt = 0; mt < 4; ++mt) {
      int nb = 64 * wm + 16 * mt + (lane >> 4) * 4;
      u32 lo = (u32)f2bf(acc[mt][nt][0] + bv) | ((u32)f2bf(acc[mt][nt][1] + bv) << 16);
      u32 hi = (u32)f2bf(acc[mt][nt][2] + bv) | ((u32)f2bf(acc[mt][nt][3] + bv) << 16);
      *(uint2*)(Tt + chl * 136 + nb) = make_uint2(lo, hi);
    }
  }
  __syncthreads();
  // coalesced store: 8 iters, 16B per thread
  for (int it = 0; it < 8; ++it) {
    int id = it * 256 + t;                 // [128 ch][2 nblk][8 chunk]
    int ch = id >> 4, nb = (id >> 3) & 1, c8 = id & 7;
    uint4 v = *(const uint4*)(Tt + ch * 136 + nb * 64 + c8 * 8);
    *(uint4*)(HioT + (size_t)((n0 >> 6) + nb) * 32768 + (size_t)(c0 + ch) * 64 + c8 * 8) = v;
  }
}

// ---------------------------------------------------------------- K3: per-batch adjacency matmul
// v2: the two independent co passes (input_in / input_out halves) are split across
// blockIdx.y -> 1024 blocks, halved per-block critical path, 3 blocks/CU (was a serial
// 2-pass chain at exactly 2 blocks/CU). Passes share only read-only As and write disjoint
// inp halves, so the unrolling is mechanically safe. A is staged twice (+17MB L3 reads).
__global__ __launch_bounds__(256) void k_amul(const float* __restrict__ Ag,
                                              const u16* __restrict__ HioT,
                                              const float* __restrict__ b_iah,
                                              const float* __restrict__ b_oah,
                                              u16* __restrict__ inp) {
  __shared__ __align__(16) u16 As[64 * 136];   // A[b]: 64 x 128 bf16, pad->136
  __shared__ __align__(16) u16 Hs[256 * 64];   // phase: HioT half (swz) ; then Tt2 [64 node][256 ch] xor16B
  int b = blockIdx.x;
  int co = blockIdx.y;
  int t = threadIdx.x, w = t >> 6, lane = t & 63;
  int rsub = lane >> 3, kofs = ((lane & 7) ^ rsub) << 3;
  {
    int r = t >> 2, q = t & 3;
    const float4* src = (const float4*)(Ag + (size_t)b * 8192 + r * 128 + q * 32);
    u16* dst = As + r * 136 + q * 32;
    for (int j = 0; j < 8; ++j) {
      float4 v = src[j];
      ushort4 o;
      o.x = f2bf(v.x); o.y = f2bf(v.y); o.z = f2bf(v.z); o.w = f2bf(v.w);
      *(ushort4*)(dst + j * 4) = o;
    }
  }
  __syncthreads();
  for (int i = 0; i < 2; ++i) {
    int rb = 64 * w + 32 * i;
    for (int s = 0; s < 4; ++s)
      async16(HioT + (size_t)b * 32768 + (size_t)(co * 256 + rb + 8 * s + rsub) * 64 + kofs,
              &Hs[(rb + 8 * s) * 64]);
  }
  __syncthreads();
  f32x4 acc[4][4];   // [ch-tile][node-tile]
  for (int a = 0; a < 4; ++a) for (int c = 0; c < 4; ++c) acc[a][c] = (f32x4)0.0f;
  for (int ks = 0; ks < 2; ++ks) {
    int c = ks * 4 + (lane >> 4);            // node-chunk
    int kk = co * 64 + ks * 32 + (lane >> 4) * 8;
    bf16x8 af[4], bf[4];
    for (int mt = 0; mt < 4; ++mt) {
      int r = 64 * w + 16 * mt + (lane & 15);   // ch row (within 256-half)
      af[mt] = *(const bf16x8*)(Hs + r * 64 + ((c ^ (r & 7)) << 3));
    }
    for (int nt = 0; nt < 4; ++nt) {
      int n = 16 * nt + (lane & 15);
      bf[nt] = *(const bf16x8*)(As + n * 136 + kk);
    }
    for (int mt = 0; mt < 4; ++mt)
      for (int nt = 0; nt < 4; ++nt)
        acc[mt][nt] = __builtin_amdgcn_mfma_f32_16x16x32_bf16(af[mt], bf[nt], acc[mt][nt], 0, 0, 0);
  }
  __syncthreads();   // done reading Hs; reuse as Tt2
  const float* bias = (co == 0) ? b_iah : b_oah;
  u16* Tt2 = Hs;     // [64 node][256 ch], 16B-chunk xor swizzle by (node&7)
  for (int mt = 0; mt < 4; ++mt) {
    int chb = 64 * w + 16 * mt + (lane >> 4) * 4;
    float b0 = bias[chb], b1 = bias[chb + 1], b2 = bias[chb + 2], b3 = bias[chb + 3];
    for (int nt = 0; nt < 4; ++nt) {
      int node = 16 * nt + (lane & 15);
      u32 lo = (u32)f2bf(acc[mt][nt][0] + b0) | ((u32)f2bf(acc[mt][nt][1] + b1) << 16);
      u32 hi = (u32)f2bf(acc[mt][nt][2] + b2) | ((u32)f2bf(acc[mt][nt][3] + b3) << 16);
      int byte = node * 512 + (((chb >> 3) ^ (node & 7)) << 4) + (chb & 7) * 2;
      *(uint2*)((char*)Tt2 + byte) = make_uint2(lo, hi);
    }
  }
  __syncthreads();
  for (int it = 0; it < 8; ++it) {
    int id = it * 256 + t;                 // [64 node][32 chunk16B]
    int node = id >> 5, c = id & 31;
    uint4 v = *(const uint4*)((char*)Tt2 + node * 512 + ((c ^ (node & 7)) << 4));
    *(uint4*)(inp + ((size_t)b * 64 + node) * 512 + co * 256 + c * 8) = v;
  }
}

// ---------------------------------------------------------------- K4: fused gate GEMM + GRU (32x32x16)
// EXACT round-0 version: the only config verified spill-free (120 arch VGPR + 128 acc,
// WRITE_SIZE 33MB, 77us). All four structural variants since (reg-prefetch W, LDS dbuf,
// K-major granules +/- sched_barrier) pinned arch VGPR at 128 and produced 330-530MB of
// scratch traffic; cause not yet isolated, so this known-good version is restored verbatim.
// acc[g][mt]: g0=i_r+h_r (K=768), g1=i_i+h_i (K=768), g2=i_n (K=512), g3=h_n (K=256).
__global__ __launch_bounds__(256, 2) void k_gates(const u16* __restrict__ inp,
                                                  const u16* __restrict__ h,
                                                  const u16* __restrict__ wcat,
                                                  const float* __restrict__ b_ih,
                                                  const float* __restrict__ b_hh,
                                                  float* __restrict__ out) {
  __shared__ __align__(16) u16 Xs[64 * 64];          // 8 KB
  __shared__ __align__(16) u16 Wslab[3 * 128 * 64];  // 48 KB (3 slabs of 16 KB)
  const u16* wih_b = wcat + 131072;   // [768,512]
  const u16* whh_b = wcat + 524288;   // [768,256]
  int m0 = blockIdx.x * 64;
  int j0 = blockIdx.y * 128;
  int t = threadIdx.x, w = t >> 6, lane = t & 63;
  int rsub8 = lane >> 3, kofs8 = ((lane & 7) ^ rsub8) << 3;
  f32x16 acc[4][2];
  for (int g = 0; g < 4; ++g) for (int mt = 0; mt < 2; ++mt) acc[g][mt] = (f32x16)0.0f;

#pragma unroll 1
  for (int kt = 0; kt < 12; ++kt) {
    bool lo = (kt < 8);
    int k0 = lo ? kt * 64 : (kt - 8) * 64;
    const u16* wb = lo ? wih_b : whh_b;
    int wp = lo ? 512 : 256;
    const u16* xb = lo ? (inp + (size_t)m0 * 512 + kt * 64)
                       : (h   + (size_t)m0 * 256 + (kt - 8) * 64);
    int xp = lo ? 512 : 256;
    // 56 async16 ops: 8 X + 3x16 W; wave w takes og = 4i+w (wave-uniform -> uniform branch)
    for (int i = 0; i < 14; ++i) {
      int og = i * 4 + w;
      if (og < 8) {
        async16(xb + (size_t)(og * 8 + rsub8) * xp + kofs8, &Xs[og * 8 * 64]);
      } else {
        int s = (og - 8) >> 4, seg = (og - 8) & 15;
        int jrow = j0 + s * 256 + seg * 8 + rsub8;
        async16(wb + (size_t)jrow * wp + k0 + kofs8, &Wslab[s * 8192 + seg * 8 * 64]);
      }
    }
    __syncthreads();
    int gl = lo ? 2 : 3;
    for (int ks = 0; ks < 4; ++ks) {
      int c = ks * 2 + (lane >> 5);
      bf16x8 af[2];
      for (int mt = 0; mt < 2; ++mt) {
        int r = 32 * mt + (lane & 31);
        af[mt] = *(const bf16x8*)(Xs + r * 64 + ((c ^ (r & 7)) << 3));
      }
      int rB = 32 * w + (lane & 31);
      int aB = rB * 64 + ((c ^ (rB & 7)) << 3);
      for (int s = 0; s < 3; ++s) {
        bf16x8 bfr = *(const bf16x8*)(Wslab + s * 8192 + aB);
        int g = (s < 2) ? s : gl;
        acc[g][0] = __builtin_amdgcn_mfma_f32_32x32x16_bf16(af[0], bfr, acc[g][0], 0, 0, 0);
        acc[g][1] = __builtin_amdgcn_mfma_f32_32x32x16_bf16(af[1], bfr, acc[g][1], 0, 0, 0);
      }
    }
    __syncthreads();
  }
  // stage h tile [64][128] into Wslab slab 2 (free after loop-end barrier)
  u16* Hh = Wslab + 2 * 8192;
  {
    int rsub4 = lane >> 4, cch = lane & 15;
    for (int i = 0; i < 4; ++i) {
      int og = i * 4 + w, r0 = og * 4;
      int kofsH = ((cch ^ ((r0 & 4) | rsub4)) << 3);
      async16(h + (size_t)(m0 + r0 + rsub4) * 256 + j0 + kofsH, &Hh[r0 * 128]);
    }
  }
  __syncthreads();
  // gates in-register; hv from Hh; hy -> F f32[64][128] (aliases Wslab slabs 0-1)
  float* F = (float*)Wslab;
  int jl = 32 * w + (lane & 31);
  int j = j0 + jl;
  float brs = b_ih[j] + b_hh[j];
  float bis = b_ih[256 + j] + b_hh[256 + j];
  float bin = b_ih[512 + j];
  float bhn = b_hh[512 + j];
  int jc = jl >> 3, je = (jl & 7) * 2;
  for (int mt = 0; mt < 2; ++mt)
    for (int e = 0; e < 16; ++e) {
      int row = (e & 3) + 8 * (e >> 2) + 4 * (lane >> 5);
      int mloc = 32 * mt + row;
      float r  = sigmoidf_(acc[0][mt][e] + brs);
      float ig = sigmoidf_(acc[1][mt][e] + bis);
      float hn = acc[3][mt][e] + bhn;
      float ng = tanhf_(acc[2][mt][e] + bin + r * hn);
      float hv = bf2f(*(const u16*)((char*)Hh + mloc * 256 + ((jc ^ (mloc & 7)) << 4) + je));
      F[mloc * 128 + jl] = ng + ig * (hv - ng);
    }
  __syncthreads();
  for (int it = 0; it < 16; ++it) {
    int id = it * 256 + t;            // [64 m][64 j-pairs]
    int mloc = id >> 6, jp = (id & 63) * 2;
    float2 v = *(const float2*)(F + mloc * 128 + jp);
    *(float2*)(out + (size_t)(m0 + mloc) * 256 + j0 + jp) = v;
  }
}

extern "C" void kernel_launch(void* const* d_in, const int* in_sizes, int n_in,
                              void* d_out, int out_size, void* d_ws, size_t ws_size,
                              hipStream_t stream) {
  (void)in_sizes; (void)n_in; (void)out_size; (void)ws_size;
  const int*   inputs = (const int*)d_in[0];
  const float* A      = (const float*)d_in[1];
  const float* emb    = (const float*)d_in[2];
  const float* W_in   = (const float*)d_in[3];
  const float* b_in   = (const float*)d_in[4];
  const float* W_out  = (const float*)d_in[5];
  const float* b_out  = (const float*)d_in[6];
  const float* w_ih   = (const float*)d_in[7];
  const float* b_ih   = (const float*)d_in[8];
  const float* w_hh   = (const float*)d_in[9];
  const float* b_hh   = (const float*)d_in[10];
  const float* b_iah  = (const float*)d_in[11];
  const float* b_oah  = (const float*)d_in[12];
  float* out = (float*)d_out;

  u16* h    = (u16*)d_ws;                 // BN*256 bf16 = 16.8 MB
  u16* HioT = h + (size_t)BN_ * HHH;      // 33.6 MB
  u16* inp  = HioT + (size_t)BN_ * H2_;   // 33.6 MB
  u16* wcat = inp + (size_t)BN_ * H2_;    // 1.44 MB

  k_convert<<<2816, 256, 0, stream>>>(W_in, W_out, w_ih, w_hh, wcat);
  k_gather_norm<<<BN_ / 4, 256, 0, stream>>>(inputs, emb, h);
  k_hio<<<dim3(BN_ / 128, 4), 256, 0, stream>>>(h, wcat, b_in, b_out, HioT);
  k_amul<<<dim3(BB, 2), 256, 0, stream>>>(A, HioT, b_iah, b_oah, inp);
  k_gates<<<dim3(BN_ / 64, 2), 256, 0, stream>>>(inp, h, wcat, b_ih, b_hh, out);
}